// Round 9
// baseline (2715.116 us; speedup 1.0000x reference)
//
#include <hip/hip_runtime.h>

// VanillaVectorQuantizer: N=131072 positions (B=32,H=64,W=64), D=64, K=512.
// enc layout [B, D, H, W]: element (b,d,p) at b*D*HW + d*HW + p, p=h*64+w.
//
// Numerics: EXACT emulation of the numpy fp32 reference chain (verified
// bitwise rounds 2-8, absmax == 0):
//   - M_k: ascending-d fp32 FMA chain (== BLAS sgemm microkernel)
//   - sq_x: numpy pairwise_sum(n=64): 8 stride-8 accumulators of pre-rounded
//     squares (mul then add, NO fma), combine ((r0+r1)+(r2+r3))+((r4+r5)+(r6+r7))
//   - sq_e: sequential d-sum of pre-rounded squares (NO fma)
//   - dist: fl(fl(sq_x - fl(2*M)) + sq_e), contraction off
//   - strict '<' ascending k == np.argmin first-index tie-break
// DO NOT alter these chains.
//
// Transport scorecard for cb (the 1:1-per-FMA operand):
//   SMEM s_load_dwordx16: 200us wall, INVARIANT to 2->8 waves/SIMD (r2/r8)
//     -> scalar-pipe throughput wall, not latency. Falsified.
//   per-lane VMEM (same-addr): 470us (r4/r7), ~17cyc/inst/CU. Falsified.
//   This round: LDS broadcast (uniform ds_read_b128, m136: same-addr = free)
//     + PPT=2 so one cb fragment feeds 8 FMAs -> cb-LDS instr = FMA/8.
// KSPLIT=4 via blockIdx.y (uniform -> sqe scalar); cb quarter (32KB) in LDS;
// 4 blocks/CU -> 4 waves/SIMD. Partials (dist_bits,k) u64, written once, no
// init; finalize kernel min-reduces ascending split (np.argmin order) and
// does the codebook gather + strided output write.

#pragma clang fp contract(off)

#define VQ_D 64
#define VQ_K 512
#define VQ_HW 4096
#define VQ_N 131072
#define KSPLIT 4
#define KRANGE 128  // VQ_K / KSPLIT

__global__ void vq_sqe_kernel(const float* __restrict__ cb,
                              float* __restrict__ sqe) {
    const int k = threadIdx.x;  // 512 threads, one block
    float s = cb[k] * cb[k];    // d = 0 (square rounded, then added: no fma)
    for (int d = 1; d < VQ_D; ++d) {
        const float v = cb[d * VQ_K + k];
        const float sq = v * v;  // contract(off): rounds the square
        s = s + sq;              // then rounds the add (numpy axis-0 reduce)
    }
    sqe[k] = s;
}

__global__ __launch_bounds__(256, 4) void vq_main_kernel(
    const float* __restrict__ enc, const float* __restrict__ cb,
    const float* __restrict__ sqe, unsigned long long* __restrict__ part) {
    __shared__ float cbs[VQ_D * KRANGE];  // 32 KB: this split's k-quarter

    const int tid = threadIdx.x;
    const int split = blockIdx.y;          // 0..3 -> SGPR, provably uniform
    const int kbase = split << 7;
    const int pos0 = blockIdx.x * 512;     // 512 positions per block
    const int b = pos0 >> 12;              // 512 | 4096: block within one b
    const int r0 = pos0 & (VQ_HW - 1);

    // Stage cb quarter into LDS (linear, float4, conflict-free writes).
    {
        const float4* src = reinterpret_cast<const float4*>(cb);  // [64][128] f4
        float4* dst = reinterpret_cast<float4*>(cbs);             // [64][32] f4
#pragma unroll
        for (int i = 0; i < 8; ++i) {
            const int idx = i * 256 + tid;   // 0..2047
            const int d = idx >> 5, c4 = idx & 31;
            dst[d * 32 + c4] = src[d * 128 + split * 32 + c4];
        }
    }
    __syncthreads();

    // Two positions per thread: A = pos0+tid, B = pos0+256+tid.
    const float* xA = enc + (size_t)b * (VQ_D * VQ_HW) + r0 + tid;
    const float* xB = xA + 256;

    // sq_x: exact numpy pairwise_sum over fl(x*x), n=64, for both positions.
    float prA[8], prB[8];
#pragma unroll
    for (int j = 0; j < 8; ++j) {
        const float a = xA[(size_t)j * VQ_HW], c = xB[(size_t)j * VQ_HW];
        prA[j] = a * a;
        prB[j] = c * c;
    }
#pragma unroll
    for (int i = 8; i < VQ_D; i += 8) {
#pragma unroll
        for (int j = 0; j < 8; ++j) {
            const float a = xA[(size_t)(i + j) * VQ_HW];
            const float c = xB[(size_t)(i + j) * VQ_HW];
            const float sa = a * a, sc = c * c;  // rounded squares
            prA[j] = prA[j] + sa;                // rounded adds
            prB[j] = prB[j] + sc;
        }
    }
    const float sqxA = ((prA[0] + prA[1]) + (prA[2] + prA[3])) +
                       ((prA[4] + prA[5]) + (prA[6] + prA[7]));
    const float sqxB = ((prB[0] + prB[1]) + (prB[2] + prB[3])) +
                       ((prB[4] + prB[5]) + (prB[6] + prB[7]));

    float bestA = 3.402823466e38f, bestB = 3.402823466e38f;
    int bkA = 0, bkB = 0;

    for (int kt = 0; kt < KRANGE; kt += 16) {
        float accA[16], accB[16];
#pragma unroll
        for (int j = 0; j < 16; ++j) accA[j] = accB[j] = 0.f;
#pragma unroll
        for (int d0 = 0; d0 < VQ_D; d0 += 4) {
            // x: 4+4 coalesced global b32 (L2/L3-resident, re-read per tile).
            float xa[4], xb[4];
#pragma unroll
            for (int dd = 0; dd < 4; ++dd) {
                xa[dd] = xA[(size_t)(d0 + dd) * VQ_HW];
                xb[dd] = xB[(size_t)(d0 + dd) * VQ_HW];
            }
#pragma unroll
            for (int dd = 0; dd < 4; ++dd) {
                // 4 uniform ds_read_b128: broadcast, conflict-free (m136).
                const float* cr = &cbs[(d0 + dd) * KRANGE + kt];
#pragma unroll
                for (int j = 0; j < 16; ++j) {  // ascending-d FMA chains
                    const float cv = cr[j];
                    accA[j] = fmaf(xa[dd], cv, accA[j]);
                    accB[j] = fmaf(xb[dd], cv, accB[j]);
                }
            }
        }
#pragma unroll
        for (int j = 0; j < 16; ++j) {
            const float m2A = 2.0f * accA[j];      // exact (power of 2)
            const float tmA = sqxA - m2A;          // rounds
            const float dA = tmA + sqe[kbase + kt + j];  // rounds (sqe: scalar)
            if (dA < bestA) { bestA = dA; bkA = kbase + kt + j; }
            const float m2B = 2.0f * accB[j];
            const float tmB = sqxB - m2B;
            const float dB = tmB + sqe[kbase + kt + j];
            if (dB < bestB) { bestB = dB; bkB = kbase + kt + j; }
        }
    }

    // Publish partials: (dist bits << 32) | k, written exactly once.
    unsigned long long* ps = part + (size_t)split * VQ_N + pos0;
    ps[tid] = ((unsigned long long)__float_as_uint(bestA) << 32) |
              (unsigned int)bkA;
    ps[256 + tid] = ((unsigned long long)__float_as_uint(bestB) << 32) |
                    (unsigned int)bkB;
}

__global__ __launch_bounds__(256) void vq_final_kernel(
    const float* __restrict__ cb, const unsigned long long* __restrict__ part,
    float* __restrict__ out) {
    const int pos = blockIdx.x * 256 + threadIdx.x;
    // Ascending split, strict '<' on exact float bits == np.argmin order.
    unsigned long long p0 = part[pos];
    float best = __uint_as_float((unsigned int)(p0 >> 32));
    int bk = (int)(p0 & 0xffffffffu);
#pragma unroll
    for (int s = 1; s < KSPLIT; ++s) {
        const unsigned long long p = part[(size_t)s * VQ_N + pos];
        const float d = __uint_as_float((unsigned int)(p >> 32));
        if (d < best) { best = d; bk = (int)(p & 0xffffffffu); }
    }
    const int b = pos >> 12;
    const int r = pos & (VQ_HW - 1);
    float* op = out + (size_t)b * (VQ_D * VQ_HW) + r;
#pragma unroll 8
    for (int d = 0; d < VQ_D; ++d)
        op[(size_t)d * VQ_HW] = cb[d * VQ_K + bk];
}

extern "C" void kernel_launch(void* const* d_in, const int* in_sizes, int n_in,
                              void* d_out, int out_size, void* d_ws, size_t ws_size,
                              hipStream_t stream) {
    const float* enc = (const float*)d_in[0];  // [32,64,64,64]
    const float* cb  = (const float*)d_in[1];  // [64,512]
    float* out = (float*)d_out;
    float* sqe = (float*)d_ws;                 // 512 floats at offset 0
    unsigned long long* part =
        (unsigned long long*)((char*)d_ws + 4096);  // 4 x 131072 x 8 B

    vq_sqe_kernel<<<1, VQ_K, 0, stream>>>(cb, sqe);
    vq_main_kernel<<<dim3(VQ_N / 512, KSPLIT), 256, 0, stream>>>(enc, cb, sqe,
                                                                 part);
    vq_final_kernel<<<VQ_N / 256, 256, 0, stream>>>(cb, part, out);
}